// Round 7
// baseline (231.596 us; speedup 1.0000x reference)
//
#include <hip/hip_runtime.h>
#include <math.h>

#define DT 0.1f

typedef __attribute__((ext_vector_type(4)))  short short4v;
typedef __attribute__((ext_vector_type(8)))  short short8;
typedef __attribute__((ext_vector_type(16))) float f32x16;

__device__ __forceinline__ short f2bf(float x) {
    unsigned int u = __float_as_uint(x);
    unsigned int r = (u + 0x7fffu + ((u >> 16) & 1u)) >> 16;  // RNE
    return (short)r;
}
__device__ __forceinline__ float bf2f(short s) {
    return __uint_as_float(((unsigned int)(unsigned short)s) << 16);
}
__device__ __forceinline__ float tanh_fast(float x) {
    float e = __expf(x + x);
    float r = __builtin_amdgcn_rcpf(e + 1.f);
    return __builtin_fmaf(-2.f, r, 1.f);
}
// HW packed f32->bf16 RNE (no builtin on gfx950; m240 recipe)
__device__ __forceinline__ unsigned cvt_pk_bf16(float a, float b) {
    unsigned r;
    asm("v_cvt_pk_bf16_f32 %0, %1, %2" : "=v"(r) : "v"(a), "v"(b));
    return r;
}
// un-sinkable global load (volatile asm)
__device__ __forceinline__ short8 ldg8(const short8* p) {
    short8 r;
    asm volatile("global_load_dwordx4 %0, %1, off" : "=v"(r) : "v"(p));
    return r;
}

// ---------------- weight packing: 32x32x16 MFMA B-fragment order -----------
__device__ __forceinline__ void pack32_body(const float* __restrict__ W,
                                            short* __restrict__ out,
                                            int K, int N, int idx, bool trans)
{
    int j = idx & 7, lane = (idx >> 3) & 63, rest = idx >> 9;
    int KT = K >> 4;
    int kt = rest % KT, nt = rest / KT;
    int k = kt * 16 + (lane >> 5) * 8 + j;
    int n = nt * 32 + (lane & 31);
    out[idx] = f2bf(trans ? W[n * K + k] : W[k * N + n]);
}

// One launch for ALL preprocessing (same block map as R1).
__global__ __launch_bounds__(256)
void prep(const float* __restrict__ W1, const float* __restrict__ W2,
          const float* __restrict__ z,
          short* __restrict__ PBSq, short* __restrict__ PBSp,
          short* __restrict__ PB2, short* __restrict__ PB2T,
          short* __restrict__ PB1q, short* __restrict__ PB1Tp,
          short* __restrict__ zpA)
{
    __shared__ short zb[32 * 520];
    const int tid = threadIdx.x;
    const int b = blockIdx.x;

    if (b < 512) {
        const int n = tid;
        float s[8];
#pragma unroll
        for (int i = 0; i < 8; ++i) s[i] = 0.f;
        int k; float coef; short* dst;
        if (b < 256) {
            k = b; coef = -0.5f * DT; dst = PBSq;
            for (int c = 0; c < 512; c += 8) {
#pragma unroll
                for (int i = 0; i < 8; ++i)
                    s[i] = __builtin_fmaf(W1[(c + i) * 256 + k],
                                          W1[(512 + c + i) * 256 + n], s[i]);
            }
        } else {
            k = b - 256; coef = DT; dst = PBSp;
            for (int c = 0; c < 512; c += 8) {
#pragma unroll
                for (int i = 0; i < 8; ++i)
                    s[i] = __builtin_fmaf(W1[(512 + c + i) * 256 + k],
                                          W1[(c + i) * 256 + n], s[i]);
            }
        }
        float v = coef * (((s[0] + s[1]) + (s[2] + s[3])) +
                          ((s[4] + s[5]) + (s[6] + s[7])));
        int kt = k >> 4, r = k & 15;
        int lane = (r >> 3) * 32 + (n & 31), nt = n >> 5;
        dst[(((nt * 16 + kt) * 64 + lane) << 3) + (r & 7)] = f2bf(v);
    } else if (b < 768) {
        pack32_body(W2, PB2, 256, 256, (b - 512) * 256 + tid, false);
    } else if (b < 1024) {
        pack32_body(W2, PB2T, 256, 256, (b - 768) * 256 + tid, true);
    } else if (b < 1536) {
        pack32_body(W1, PB1q, 512, 256, (b - 1024) * 256 + tid, false);
    } else if (b < 2048) {
        pack32_body(W1 + 512 * 256, PB1Tp, 256, 512, (b - 1536) * 256 + tid, true);
    } else {
        const int bx = b - 2048;               // 512 blocks x 32 rows
#pragma unroll
        for (int j = 0; j < 16; ++j) {
            int lin = j * 256 + tid;           // 4096 float4
            int r = lin >> 7, c4 = lin & 127;
            float4 v = ((const float4*)z)[(size_t)(bx * 32 + r) * 128 + c4];
            uint2 pk;
            pk.x = cvt_pk_bf16(v.x, v.y);
            pk.y = cvt_pk_bf16(v.z, v.w);
            *(uint2*)&zb[r * 520 + c4 * 4] = pk;
        }
        __syncthreads();
        const int lane = tid & 63, w = tid >> 6;
        const int m = lane & 31, lh = lane >> 5;
#pragma unroll
        for (int j = 0; j < 8; ++j) {
            int kt = w * 8 + j;
            short8 f = *(const short8*)&zb[m * 520 + kt * 16 + lh * 8];
            *(short8*)(zpA + (((size_t)bx * 32 + kt) * 64 + lane) * 8) = f;
        }
    }
}

// ---------------- 64-row LDS tile layout (staging / out-gemm) --------------
__device__ __forceinline__ short8 lds_frag(const short* Ac, int kt, int mt2,
                                           int l31, int lh, int rot)
{
    int nt_s = kt >> 1;
    int po = (((kt & 1) * 2 + lh) * 4 + rot) & 15;
    int base = ((nt_s * 2 + mt2) * 64 + l31) * 16 + po;
    short4v x = *(const short4v*)&Ac[base];
    short4v y = *(const short4v*)&Ac[base + 512];
    short8 r;
    r[0] = x.x; r[1] = x.y; r[2] = x.z; r[3] = x.w;
    r[4] = y.x; r[5] = y.y; r[6] = y.z; r[7] = y.w;
    return r;
}
__device__ __forceinline__ void store_tile(short* Ac, int nt, int mt2, int lane,
                                           int rot, const f32x16 v)
{
    int base = ((nt * 2 + mt2) * 64 + lane) * 16;
#pragma unroll
    for (int c = 0; c < 4; ++c) {
        uint2 pk;
        pk.x = cvt_pk_bf16(v[4 * c + 0], v[4 * c + 1]);
        pk.y = cvt_pk_bf16(v[4 * c + 2], v[4 * c + 3]);
        *(uint2*)&Ac[base + ((4 * c + rot) & 15)] = pk;
    }
}

// ---------------- 32-row LDS tile layout (main loop; verified R2/R3) -------
__device__ __forceinline__ short8 lds_frag32(const short* Ac, int kt,
                                             int l31, int lh, int rot)
{
    int nt_s = kt >> 1;
    int po = (((kt & 1) * 2 + lh) * 4 + rot) & 15;
    int base = (nt_s * 64 + l31) * 16 + po;
    short4v x = *(const short4v*)&Ac[base];
    short4v y = *(const short4v*)&Ac[base + 512];
    short8 r;
    r[0] = x.x; r[1] = x.y; r[2] = x.z; r[3] = x.w;
    r[4] = y.x; r[5] = y.y; r[6] = y.z; r[7] = y.w;
    return r;
}
__device__ __forceinline__ void store_tile32(short* Ac, int nt, int lane,
                                             int rot, const f32x16 v)
{
    int base = (nt * 64 + lane) * 16;
#pragma unroll
    for (int c = 0; c < 4; ++c) {
        uint2 pk;
        pk.x = cvt_pk_bf16(v[4 * c + 0], v[4 * c + 1]);
        pk.y = cvt_pk_bf16(v[4 * c + 2], v[4 * c + 3]);
        *(uint2*)&Ac[base + ((4 * c + rot) & 15)] = pk;
    }
}

// ---- fused phase: one 32x32-tile gemm (K=256) + interleaved VALU task -----
// The VALU slices (one output element each) are issued IN PROGRAM ORDER
// between MFMAs, so the VALU/trans pipes fill the MFMA dependency-chain and
// B-load latency gaps (T15 mechanism). Slices 0..3 are hoisted before the
// first vmcnt wait to cover the L2 fill.
// INVARIANT: no other VMEM inside (exact vmcnt counting); entry drain guard.
template <typename F>
__device__ __forceinline__ void gemm_f(const short* Ac, int l31, int lh, int rot,
                                       const short8* __restrict__ Bf,
                                       f32x16& acc, F valu)
{
    asm volatile("s_waitcnt vmcnt(0)" ::: "memory");
    short8 pb[8];
#pragma unroll
    for (int k = 0; k < 8; ++k) pb[k] = ldg8(Bf + k * 64);
    short8 pa0 = lds_frag32(Ac, 0, l31, lh, rot);
    short8 pa1 = lds_frag32(Ac, 1, l31, lh, rot);
    valu(0); valu(1); valu(2); valu(3);
#pragma unroll
    for (int kt = 0; kt < 16; ++kt) {
        if (kt < 12) valu(kt + 4);
        const int N = (15 - kt) < 7 ? (15 - kt) : 7;
        asm volatile("s_waitcnt vmcnt(%1)" : "+v"(pb[kt & 7]) : "i"(N));
        short8 cb = pb[kt & 7];
        if (kt + 8 < 16) pb[kt & 7] = ldg8(Bf + (kt + 8) * 64);
        short8 ca = pa0;
        pa0 = pa1;
        if (kt + 2 < 16) pa1 = lds_frag32(Ac, kt + 2, l31, lh, rot);
        acc = __builtin_amdgcn_mfma_f32_32x32x16_bf16(ca, cb, acc, 0, 0, 0);
    }
}

// ---------------- fused leapfrog: two staggered 32-row groups --------------
// 6 phases/iter, each = gemm(RG_x) MFMA-stream ∥ elementwise(RG_y) VALU:
//  A: G2a∥V1b  B: G2b∥V2a  C: G3a∥V2b  D: G3b∥V3a  E: G4a∥V3b  F: G4b∥V1a
__global__ __launch_bounds__(512, 1)
void mega(const short* __restrict__ zpA,
          const short* __restrict__ PB1q,
          const short* __restrict__ PB2,
          const short* __restrict__ PB2T,
          const short* __restrict__ PBSq,
          const short* __restrict__ PBSp,
          const float* __restrict__ b1,
          const float* __restrict__ b2,
          const float* __restrict__ W3,
          const short* __restrict__ PB1Tp,
          const float* __restrict__ z,
          float* __restrict__ out)
{
    __shared__ alignas(16) short smem[32768];   // 64 KB
    short* h1_a  = smem;                        // 32-row tiles, 8 KB each
    short* h1_b  = smem + 4096;
    short* da2_a = smem + 8192;
    short* da2_b = smem + 12288;
    short* da1_a = smem + 16384;
    short* da1_b = smem + 20480;                // loop uses 48 KB

    const int tid = threadIdx.x;
    const int lane = tid & 63, w = tid >> 6;   // w = nt strip, 0..7
    const int l31 = lane & 31, lh = lane >> 5;
    const int rot = ((l31 >> 2) & 3) * 4;
    const int bx = blockIdx.x;

    const int col = w * 32 + l31;
    const float b1v = b1[col], b2v = b2[col], w3v = W3[col];
    const int basei = (w * 64 + lane) * 16;    // own-tile base, 32-row layout

    const short8* BfPB2  = (const short8*)PB2  + ((size_t)w * 16) * 64 + lane;
    const short8* BfPB2T = (const short8*)PB2T + ((size_t)w * 16) * 64 + lane;
    const short8* BfSq   = (const short8*)PBSq + ((size_t)w * 16) * 64 + lane;
    const short8* BfSp   = (const short8*)PBSp + ((size_t)w * 16) * 64 + lane;

    f32x16 A1a = 0.f, A1b = 0.f;
    f32x16 dsa = 0.f, dsb = 0.f;

    // GEMM1: A1{a,b} = z @ W1[:512,:]  (K=512, plain compiler-managed loads)
    {
        const short8* Af0 = (const short8*)zpA + ((size_t)(bx * 2 + 0) * 32) * 64 + lane;
        const short8* Af1 = (const short8*)zpA + ((size_t)(bx * 2 + 1) * 32) * 64 + lane;
        const short8* Bf  = (const short8*)PB1q + ((size_t)w * 32) * 64 + lane;
        short8 pa0[2], pa1[2], pb[4];
#pragma unroll
        for (int k = 0; k < 2; ++k) { pa0[k] = Af0[k * 64]; pa1[k] = Af1[k * 64]; }
#pragma unroll
        for (int k = 0; k < 4; ++k) pb[k] = Bf[k * 64];
#pragma unroll
        for (int kt = 0; kt < 32; ++kt) {
            short8 ca0 = pa0[kt & 1], ca1 = pa1[kt & 1], cb = pb[kt & 3];
            if (kt + 2 < 32) {
                pa0[kt & 1] = Af0[(kt + 2) * 64];
                pa1[kt & 1] = Af1[(kt + 2) * 64];
            }
            if (kt + 4 < 32) pb[kt & 3] = Bf[(kt + 4) * 64];
            A1a = __builtin_amdgcn_mfma_f32_32x32x16_bf16(ca0, cb, A1a, 0, 0, 0);
            A1b = __builtin_amdgcn_mfma_f32_32x32x16_bf16(ca1, cb, A1b, 0, 0, 0);
        }
    }

    // prologue: V1a (h1_a = tanh(A1a + b1))
    {
        f32x16 d;
#pragma unroll
        for (int r = 0; r < 16; ++r) d[r] = tanh_fast(A1a[r] + b1v);
        store_tile32(h1_a, w, lane, rot, d);
    }
    __syncthreads();

    f32x16 u_b = 0.f;   // carried G3b output (phase D -> E)

    for (int it = 0; it < 8; ++it) {
        const bool isq = ((it % 3) == 1);
        const short8* BfS = isq ? BfSp : BfSq;
        f32x16 t_a = 0.f, t_b = 0.f, u_a = 0.f;
        f32x16 d;
        short4v h4;

        // Phase A: G2a (t_a = h1_a @ W2) ∥ V1b (d = tanh(A1b+b1) -> h1_b)
        gemm_f(h1_a, l31, lh, rot, BfPB2, t_a, [&](int kt) {
            d[kt] = tanh_fast(A1b[kt] + b1v);
        });
        store_tile32(h1_b, w, lane, rot, d);
        __syncthreads();

        // Phase B: G2b ∥ V2a (d = W3*(1-tanh^2(t_a+b2)) -> da2_a)
        gemm_f(h1_b, l31, lh, rot, BfPB2, t_b, [&](int kt) {
            float ta = tanh_fast(t_a[kt] + b2v);
            d[kt] = w3v * (1.f - ta * ta);
        });
        store_tile32(da2_a, w, lane, rot, d);
        __syncthreads();

        // Phase C: G3a (u_a = da2_a @ W2^T) ∥ V2b (-> da2_b)
        gemm_f(da2_a, l31, lh, rot, BfPB2T, u_a, [&](int kt) {
            float ta = tanh_fast(t_b[kt] + b2v);
            d[kt] = w3v * (1.f - ta * ta);
        });
        store_tile32(da2_b, w, lane, rot, d);
        __syncthreads();

        // Phase D: G3b ∥ V3a (d = u_a*(1-h1_a^2) -> da1_a, dsum)
        u_b = 0.f;
        gemm_f(da2_b, l31, lh, rot, BfPB2T, u_b, [&](int kt) {
            if ((kt & 3) == 0)
                h4 = *(const short4v*)&h1_a[basei + ((kt + rot) & 15)];
            float h = bf2f((kt & 3) == 0 ? h4.x : (kt & 3) == 1 ? h4.y
                         : (kt & 3) == 2 ? h4.z : h4.w);
            d[kt] = u_a[kt] * (1.f - h * h);
        });
        if (isq) dsa += d;
        store_tile32(da1_a, w, lane, rot, d);
        __syncthreads();

        if (it < 7) {
            // Phase E: G4a (A1a += da1_a @ S) ∥ V3b (-> da1_b, dsum)
            gemm_f(da1_a, l31, lh, rot, BfS, A1a, [&](int kt) {
                if ((kt & 3) == 0)
                    h4 = *(const short4v*)&h1_b[basei + ((kt + rot) & 15)];
                float h = bf2f((kt & 3) == 0 ? h4.x : (kt & 3) == 1 ? h4.y
                             : (kt & 3) == 2 ? h4.z : h4.w);
                d[kt] = u_b[kt] * (1.f - h * h);
            });
            if (isq) dsb += d;
            store_tile32(da1_b, w, lane, rot, d);
            __syncthreads();

            // Phase F: G4b (A1b += da1_b @ S) ∥ V1a (next iter h1_a)
            gemm_f(da1_b, l31, lh, rot, BfS, A1b, [&](int kt) {
                d[kt] = tanh_fast(A1a[kt] + b1v);
            });
            store_tile32(h1_a, w, lane, rot, d);
            __syncthreads();
        } else {
            // it == 7 (a q-eval): plain V3b, no further gemms needed
#pragma unroll
            for (int kt = 0; kt < 16; ++kt) {
                if ((kt & 3) == 0)
                    h4 = *(const short4v*)&h1_b[basei + ((kt + rot) & 15)];
                float h = bf2f((kt & 3) == 0 ? h4.x : (kt & 3) == 1 ? h4.y
                             : (kt & 3) == 2 ? h4.z : h4.w);
                d[kt] = u_b[kt] * (1.f - h * h);
            }
            dsb += d;                      // isq true at it=7
            __syncthreads();               // all h1_b reads done pre-staging
        }
    }

    // ---- fused out-gemm: C = dsum @ W1^T[:,512:], out = z + DT*C ----------
    // stage dsum in 64-row A-frag layout over smem[0..16384) (all dead now)
    store_tile(smem, w, 0, lane, rot, dsa);
    store_tile(smem, w, 1, lane, rot, dsb);
    __syncthreads();

    const int mt = w >> 2;           // 0,0,0,0,1,1,1,1 row-group
    const int nq = w & 3;            // col quarter
    {
        const short8* Bf0 = (const short8*)PB1Tp + (size_t)(nq * 4 + 0) * 16 * 64 + lane;
        const short8* Bf1 = (const short8*)PB1Tp + (size_t)(nq * 4 + 1) * 16 * 64 + lane;
        const short8* Bf2 = (const short8*)PB1Tp + (size_t)(nq * 4 + 2) * 16 * 64 + lane;
        const short8* Bf3 = (const short8*)PB1Tp + (size_t)(nq * 4 + 3) * 16 * 64 + lane;
        f32x16 acc4[4];
#pragma unroll
        for (int t = 0; t < 4; ++t) acc4[t] = 0.f;
        short8 br[2][4];
#pragma unroll
        for (int k = 0; k < 2; ++k) {
            br[k][0] = Bf0[k * 64]; br[k][1] = Bf1[k * 64];
            br[k][2] = Bf2[k * 64]; br[k][3] = Bf3[k * 64];
        }
#pragma unroll
        for (int kt = 0; kt < 16; ++kt) {
            short8 a = lds_frag(smem, kt, mt, l31, lh, rot);
            short8 bb[4];
#pragma unroll
            for (int t = 0; t < 4; ++t) bb[t] = br[kt & 1][t];
            if (kt + 2 < 16) {
                br[kt & 1][0] = Bf0[(kt + 2) * 64];
                br[kt & 1][1] = Bf1[(kt + 2) * 64];
                br[kt & 1][2] = Bf2[(kt + 2) * 64];
                br[kt & 1][3] = Bf3[(kt + 2) * 64];
            }
#pragma unroll
            for (int t = 0; t < 4; ++t)
                acc4[t] = __builtin_amdgcn_mfma_f32_32x32x16_bf16(a, bb[t], acc4[t], 0, 0, 0);
        }
        __syncthreads();   // staged-frag reads done before Ct overwrite

        // coalesced epilogue via LDS fp32 (full 64 KB)
        float* Ct = (float*)smem;                 // 32 x 512 fp32
#pragma unroll
        for (int p = 0; p < 2; ++p) {
            if (mt == p) {
#pragma unroll
                for (int t = 0; t < 4; ++t) {
                    const int c = (nq * 4 + t) * 32 + l31;
#pragma unroll
                    for (int r = 0; r < 16; ++r) {
                        int row = (r & 3) + 8 * (r >> 2) + 4 * lh;
                        Ct[row * 512 + c] = acc4[t][r];
                    }
                }
            }
            __syncthreads();
#pragma unroll
            for (int j = 0; j < 8; ++j) {
                int lin = j * 512 + tid;          // 4096 float4
                int r = lin >> 7, c4 = lin & 127;
                size_t gi = (size_t)(bx * 64 + p * 32 + r) * 128 + c4;
                float4 zv = ((const float4*)z)[gi];
                float4 cv = *(const float4*)&Ct[r * 512 + c4 * 4];
                float4 ov;
                ov.x = zv.x + DT * cv.x; ov.y = zv.y + DT * cv.y;
                ov.z = zv.z + DT * cv.z; ov.w = zv.w + DT * cv.w;
                ((float4*)out)[gi] = ov;
            }
            __syncthreads();
        }
    }
}

extern "C" void kernel_launch(void* const* d_in, const int* in_sizes, int n_in,
                              void* d_out, int out_size, void* d_ws, size_t ws_size,
                              hipStream_t stream)
{
    const float* z  = (const float*)d_in[0];
    const float* W1 = (const float*)d_in[1];   // 1024 x 256
    const float* b1 = (const float*)d_in[2];
    const float* W2 = (const float*)d_in[3];   // 256 x 256
    const float* b2 = (const float*)d_in[4];
    const float* W3 = (const float*)d_in[5];   // 256 x 1
    float* out = (float*)d_out;

    short* PB2   = (short*)d_ws;
    short* PB2T  = PB2   + 65536;
    short* PBSq  = PB2T  + 65536;
    short* PBSp  = PBSq  + 65536;
    short* PB1q  = PBSp  + 65536;              // K=512,N=256
    short* PB1Tp = PB1q  + 131072;             // K=256,N=512
    short* zpA   = PB1Tp + 131072;             // 16 MB

    prep<<<2560, 256, 0, stream>>>(W1, W2, z, PBSq, PBSp, PB2, PB2T,
                                   PB1q, PB1Tp, zpA);
    mega<<<256, 512, 0, stream>>>(zpA, PB1q, PB2, PB2T, PBSq, PBSp,
                                  b1, b2, W3, PB1Tp, z, out);
}

// Round 8
// 228.395 us; speedup vs baseline: 1.0140x; 1.0140x over previous
//
#include <hip/hip_runtime.h>
#include <math.h>

#define DT 0.1f

typedef __attribute__((ext_vector_type(4)))  short short4v;
typedef __attribute__((ext_vector_type(8)))  short short8;
typedef __attribute__((ext_vector_type(16))) float f32x16;

__device__ __forceinline__ short f2bf(float x) {
    unsigned int u = __float_as_uint(x);
    unsigned int r = (u + 0x7fffu + ((u >> 16) & 1u)) >> 16;  // RNE
    return (short)r;
}
__device__ __forceinline__ float bf2f(short s) {
    return __uint_as_float(((unsigned int)(unsigned short)s) << 16);
}
__device__ __forceinline__ float tanh_fast(float x) {
    float e = __expf(x + x);
    float r = __builtin_amdgcn_rcpf(e + 1.f);
    return __builtin_fmaf(-2.f, r, 1.f);
}
// HW packed f32->bf16 RNE (no builtin on gfx950)
__device__ __forceinline__ unsigned cvt_pk_bf16(float a, float b) {
    unsigned r;
    asm("v_cvt_pk_bf16_f32 %0, %1, %2" : "=v"(r) : "v"(a), "v"(b));
    return r;
}

// ---------------- weight packing: 32x32x16 MFMA B-fragment order -----------
// lane holds B[k = kt*16 + (lane>>5)*8 + j][n = nt*32 + (lane&31)]
// at out[((nt*KT + kt)*64 + lane)*8 + j],  KT = K/16
__device__ __forceinline__ void pack32_body(const float* __restrict__ W,
                                            short* __restrict__ out,
                                            int K, int N, int idx, bool trans)
{
    int j = idx & 7, lane = (idx >> 3) & 63, rest = idx >> 9;
    int KT = K >> 4;
    int kt = rest % KT, nt = rest / KT;
    int k = kt * 16 + (lane >> 5) * 8 + j;
    int n = nt * 32 + (lane & 31);
    out[idx] = f2bf(trans ? W[n * K + k] : W[k * N + n]);
}

// One launch for ALL preprocessing (same block map as R1).
__global__ __launch_bounds__(256)
void prep(const float* __restrict__ W1, const float* __restrict__ W2,
          const float* __restrict__ z,
          short* __restrict__ PBSq, short* __restrict__ PBSp,
          short* __restrict__ PB2, short* __restrict__ PB2T,
          short* __restrict__ PB1q, short* __restrict__ PB1Tp,
          short* __restrict__ zpA)
{
    __shared__ short zb[32 * 520];
    const int tid = threadIdx.x;
    const int b = blockIdx.x;

    if (b < 512) {
        // S_qp = -0.5*dt * W1^T[:, :512] @ W1[512:, :]   (b <  256, k = b)
        // S_pq =      dt * W1^T[:, 512:] @ W1[:512, :]   (b >= 256, k = b-256)
        const int n = tid;
        float s[8];
#pragma unroll
        for (int i = 0; i < 8; ++i) s[i] = 0.f;
        int k; float coef; short* dst;
        if (b < 256) {
            k = b; coef = -0.5f * DT; dst = PBSq;
            for (int c = 0; c < 512; c += 8) {
#pragma unroll
                for (int i = 0; i < 8; ++i)
                    s[i] = __builtin_fmaf(W1[(c + i) * 256 + k],
                                          W1[(512 + c + i) * 256 + n], s[i]);
            }
        } else {
            k = b - 256; coef = DT; dst = PBSp;
            for (int c = 0; c < 512; c += 8) {
#pragma unroll
                for (int i = 0; i < 8; ++i)
                    s[i] = __builtin_fmaf(W1[(512 + c + i) * 256 + k],
                                          W1[(c + i) * 256 + n], s[i]);
            }
        }
        float v = coef * (((s[0] + s[1]) + (s[2] + s[3])) +
                          ((s[4] + s[5]) + (s[6] + s[7])));
        int kt = k >> 4, r = k & 15;
        int lane = (r >> 3) * 32 + (n & 31), nt = n >> 5;
        dst[(((nt * 16 + kt) * 64 + lane) << 3) + (r & 7)] = f2bf(v);
    } else if (b < 768) {
        pack32_body(W2, PB2, 256, 256, (b - 512) * 256 + tid, false);
    } else if (b < 1024) {
        pack32_body(W2, PB2T, 256, 256, (b - 768) * 256 + tid, true);
    } else if (b < 1536) {
        pack32_body(W1, PB1q, 512, 256, (b - 1024) * 256 + tid, false);
    } else if (b < 2048) {
        pack32_body(W1 + 512 * 256, PB1Tp, 256, 512, (b - 1536) * 256 + tid, true);
    } else {
        // z (16384x512 fp32) -> A-frag-packed bf16, coalesced via LDS staging.
        const int bx = b - 2048;               // 512 blocks x 32 rows
#pragma unroll
        for (int j = 0; j < 16; ++j) {
            int lin = j * 256 + tid;           // 4096 float4
            int r = lin >> 7, c4 = lin & 127;
            float4 v = ((const float4*)z)[(size_t)(bx * 32 + r) * 128 + c4];
            uint2 pk;
            pk.x = cvt_pk_bf16(v.x, v.y);
            pk.y = cvt_pk_bf16(v.z, v.w);
            *(uint2*)&zb[r * 520 + c4 * 4] = pk;
        }
        __syncthreads();
        const int lane = tid & 63, w = tid >> 6;
        const int m = lane & 31, lh = lane >> 5;
#pragma unroll
        for (int j = 0; j < 8; ++j) {
            int kt = w * 8 + j;
            short8 f = *(const short8*)&zb[m * 520 + kt * 16 + lh * 8];
            *(short8*)(zpA + (((size_t)bx * 32 + kt) * 64 + lane) * 8) = f;
        }
    }
}

// ---------------- LDS tile layout, 32-row block version (verified R2/R3) ---
// tile nt: 64 slots x 16 shorts; rot = ((l31>>2)&3)*4
__device__ __forceinline__ short8 lds_frag32(const short* Ac, int kt,
                                             int l31, int lh, int rot)
{
    int nt_s = kt >> 1;
    int po = (((kt & 1) * 2 + lh) * 4 + rot) & 15;
    int base = (nt_s * 64 + l31) * 16 + po;
    short4v x = *(const short4v*)&Ac[base];
    short4v y = *(const short4v*)&Ac[base + 512];   // slot l31+32, same tile
    short8 r;
    r[0] = x.x; r[1] = x.y; r[2] = x.z; r[3] = x.w;
    r[4] = y.x; r[5] = y.y; r[6] = y.z; r[7] = y.w;
    return r;
}
__device__ __forceinline__ void store_tile32(short* Ac, int nt, int lane,
                                             int rot, const f32x16 v)
{
    int base = (nt * 64 + lane) * 16;
#pragma unroll
    for (int c = 0; c < 4; ++c) {
        uint2 pk;
        pk.x = cvt_pk_bf16(v[4 * c + 0], v[4 * c + 1]);
        pk.y = cvt_pk_bf16(v[4 * c + 2], v[4 * c + 3]);
        *(uint2*)&Ac[base + ((4 * c + rot) & 15)] = pk;
    }
}

// K=256 gemm, single 32x32 output tile per wave.
// SLIM register footprint: pb[4] (16 VGPR), pa depth 2 (8 VGPR) — sized so
// VGPR<=64 and acc/A1/dsum live in AGPR: total/wave ~112 <= 128
// -> 4 waves/SIMD co-residency (2 blocks/CU), the R1-R7 occupancy wall.
__device__ __forceinline__ void gemm_nt32(const short* Ac, int l31, int lh, int rot,
                                          const short8* __restrict__ Bf, f32x16& acc)
{
    short8 pb[4];
#pragma unroll
    for (int k = 0; k < 4; ++k) pb[k] = Bf[k * 64];
    short8 pa0 = lds_frag32(Ac, 0, l31, lh, rot);
    short8 pa1 = lds_frag32(Ac, 1, l31, lh, rot);
#pragma unroll
    for (int kt = 0; kt < 16; ++kt) {
        short8 ca = pa0, cb = pb[kt & 3];
        pa0 = pa1;
        if (kt + 2 < 16) pa1 = lds_frag32(Ac, kt + 2, l31, lh, rot);
        if (kt + 4 < 16) pb[kt & 3] = Bf[(kt + 4) * 64];
        acc = __builtin_amdgcn_mfma_f32_32x32x16_bf16(ca, cb, acc, 0, 0, 0);
    }
}

// ---------------- fused leapfrog: 32 rows/block, 512 blocks ----------------
// __launch_bounds__(512, 4): empirically cap = 256/arg2 = 64 VGPR. R2 failed
// at this cap because demand was ~100 VGPR (deep prefetch) -> huge spills.
// This version's demand is ~60 VGPR + 48 AGPR accumulators = ~112 total,
// which fits 4 waves/SIMD (floor(512/112) >= 4). Spill tripwire:
// FETCH_SIZE must stay ~30 MB and WRITE_SIZE ~33 MB.
__global__ __launch_bounds__(512, 4)
void mega(const short* __restrict__ zpA,
          const short* __restrict__ PB1q,
          const short* __restrict__ PB2,
          const short* __restrict__ PB2T,
          const short* __restrict__ PBSq,
          const short* __restrict__ PBSp,
          const float* __restrict__ b1,
          const float* __restrict__ b2,
          const float* __restrict__ W3,
          const short* __restrict__ PB1Tp,
          const float* __restrict__ z,
          float* __restrict__ out)
{
    __shared__ alignas(16) short smem[16384];   // 32 KB -> 2 blocks/CU LDS-ok
    short* h1_c = smem;             // 8 nt x 64 x 16
    short* da_c = smem + 8192;

    const int tid = threadIdx.x;
    const int lane = tid & 63, w = tid >> 6;   // w = nt strip, 0..7
    const int l31 = lane & 31, lh = lane >> 5;
    const int rot = ((l31 >> 2) & 3) * 4;
    const int bx = blockIdx.x;                 // 512 blocks x 32 rows

    const int col = w * 32 + l31;
    const float b1v = b1[col], b2v = b2[col], w3v = W3[col];

    f32x16 A1 = 0.f;
    f32x16 dsum = 0.f;

    // GEMM1: A1 = z @ W1[:512,:]  (K=512, A frags from global, KT=32)
    {
        const short8* Af = (const short8*)zpA + ((size_t)bx * 32) * 64 + lane;
        const short8* Bf = (const short8*)PB1q + ((size_t)w * 32) * 64 + lane;
        short8 pa[2], pb[4];
#pragma unroll
        for (int k = 0; k < 2; ++k) pa[k] = Af[k * 64];
#pragma unroll
        for (int k = 0; k < 4; ++k) pb[k] = Bf[k * 64];
#pragma unroll
        for (int kt = 0; kt < 32; ++kt) {
            short8 ca = pa[kt & 1], cb = pb[kt & 3];
            if (kt + 2 < 32) pa[kt & 1] = Af[(kt + 2) * 64];
            if (kt + 4 < 32) pb[kt & 3] = Bf[(kt + 4) * 64];
            A1 = __builtin_amdgcn_mfma_f32_32x32x16_bf16(ca, cb, A1, 0, 0, 0);
        }
    }

    for (int it = 0; it < 8; ++it) {
        const bool isq = ((it % 3) == 1);

        // P1: h1 = tanh(A1 + b1)
        {
            f32x16 hv;
#pragma unroll
            for (int r = 0; r < 16; ++r) hv[r] = tanh_fast(A1[r] + b1v);
            store_tile32(h1_c, w, lane, rot, hv);
        }
        __syncthreads();

        // P2: da2 = W3*(1-tanh^2(h1@W2 + b2))
        {
            f32x16 t0 = 0.f;
            gemm_nt32(h1_c, l31, lh, rot,
                      (const short8*)PB2 + ((size_t)w * 16) * 64 + lane, t0);
            f32x16 d;
#pragma unroll
            for (int r = 0; r < 16; ++r) {
                float ta = tanh_fast(t0[r] + b2v);
                d[r] = w3v * (1.f - ta * ta);
            }
            store_tile32(da_c, w, lane, rot, d);
        }
        __syncthreads();

        // P3: da1 = (da2@W2^T) * (1-h1^2)
        {
            f32x16 t0 = 0.f;
            gemm_nt32(da_c, l31, lh, rot,
                      (const short8*)PB2T + ((size_t)w * 16) * 64 + lane, t0);
            __syncthreads();   // all waves done reading da2
            f32x16 d;
            const int basei = (w * 64 + lane) * 16;
#pragma unroll
            for (int c = 0; c < 4; ++c) {
                short4v h4 = *(const short4v*)&h1_c[basei + ((4 * c + rot) & 15)];
                float h0 = bf2f(h4.x), h1f = bf2f(h4.y);
                float h2 = bf2f(h4.z), h3 = bf2f(h4.w);
                d[4 * c + 0] = t0[4 * c + 0] * (1.f - h0 * h0);
                d[4 * c + 1] = t0[4 * c + 1] * (1.f - h1f * h1f);
                d[4 * c + 2] = t0[4 * c + 2] * (1.f - h2 * h2);
                d[4 * c + 3] = t0[4 * c + 3] * (1.f - h3 * h3);
            }
            if (isq) dsum += d;
            store_tile32(da_c, w, lane, rot, d);
        }
        __syncthreads();

        // P4: A1 += da1 @ S  (coef folded into S; skip on last eval)
        if (it < 7) {
            const short* S = isq ? PBSp : PBSq;
            gemm_nt32(da_c, l31, lh, rot,
                      (const short8*)S + ((size_t)w * 16) * 64 + lane, A1);
            // safe: every wave's P4 reads complete before it reaches the
            // next-iteration P1 barrier, which precedes any da_c overwrite.
        }
    }

    // ---- fused out-gemm: C = dsum @ W1^T[:,512:], out = z + DT*C ----------
    store_tile32(da_c, w, lane, rot, dsum);
    __syncthreads();

    // wave w -> output col-tiles {2w, 2w+1} (cols [w*64, w*64+64))
    f32x16 acc2[2];
    acc2[0] = 0.f; acc2[1] = 0.f;
    {
        const short8* Bf0 = (const short8*)PB1Tp + (size_t)(2 * w + 0) * 16 * 64 + lane;
        const short8* Bf1 = (const short8*)PB1Tp + (size_t)(2 * w + 1) * 16 * 64 + lane;
        short8 pb0[2], pb1[2];
#pragma unroll
        for (int k = 0; k < 2; ++k) { pb0[k] = Bf0[k * 64]; pb1[k] = Bf1[k * 64]; }
        short8 pa0 = lds_frag32(da_c, 0, l31, lh, rot);
        short8 pa1 = lds_frag32(da_c, 1, l31, lh, rot);
#pragma unroll
        for (int kt = 0; kt < 16; ++kt) {
            short8 ca = pa0, cb0 = pb0[kt & 1], cb1 = pb1[kt & 1];
            pa0 = pa1;
            if (kt + 2 < 16) pa1 = lds_frag32(da_c, kt + 2, l31, lh, rot);
            if (kt + 2 < 16) {
                pb0[kt & 1] = Bf0[(kt + 2) * 64];
                pb1[kt & 1] = Bf1[(kt + 2) * 64];
            }
            acc2[0] = __builtin_amdgcn_mfma_f32_32x32x16_bf16(ca, cb0, acc2[0], 0, 0, 0);
            acc2[1] = __builtin_amdgcn_mfma_f32_32x32x16_bf16(ca, cb1, acc2[1], 0, 0, 0);
        }
    }
    __syncthreads();   // all A-frag reads of da_c done before Ct overwrite

    // coalesced epilogue via LDS fp32 (reuses the 32 KB), two 256-col passes
    float* Ct = (float*)smem;                 // 32 x 256 fp32 = 32 KB
#pragma unroll
    for (int p = 0; p < 2; ++p) {
        if ((w >> 2) == p) {                  // waves owning cols [p*256, p*256+256)
#pragma unroll
            for (int t = 0; t < 2; ++t) {
                const int cl = (w & 3) * 64 + t * 32 + l31;
#pragma unroll
                for (int r = 0; r < 16; ++r) {
                    int row = (r & 3) + 8 * (r >> 2) + 4 * lh;
                    Ct[row * 256 + cl] = acc2[t][r];
                }
            }
        }
        __syncthreads();
#pragma unroll
        for (int j = 0; j < 4; ++j) {
            int lin = j * 512 + tid;          // 2048 float4 per pass
            int r = lin >> 6, c4 = lin & 63;
            size_t gi = (size_t)(bx * 32 + r) * 128 + p * 64 + c4;
            float4 zv = ((const float4*)z)[gi];
            float4 cv = *(const float4*)&Ct[r * 256 + c4 * 4];
            float4 ov;
            ov.x = zv.x + DT * cv.x; ov.y = zv.y + DT * cv.y;
            ov.z = zv.z + DT * cv.z; ov.w = zv.w + DT * cv.w;
            ((float4*)out)[gi] = ov;
        }
        __syncthreads();
    }
}

extern "C" void kernel_launch(void* const* d_in, const int* in_sizes, int n_in,
                              void* d_out, int out_size, void* d_ws, size_t ws_size,
                              hipStream_t stream)
{
    const float* z  = (const float*)d_in[0];
    const float* W1 = (const float*)d_in[1];   // 1024 x 256
    const float* b1 = (const float*)d_in[2];
    const float* W2 = (const float*)d_in[3];   // 256 x 256
    const float* b2 = (const float*)d_in[4];
    const float* W3 = (const float*)d_in[5];   // 256 x 1
    float* out = (float*)d_out;

    short* PB2   = (short*)d_ws;
    short* PB2T  = PB2   + 65536;
    short* PBSq  = PB2T  + 65536;
    short* PBSp  = PBSq  + 65536;
    short* PB1q  = PBSp  + 65536;              // K=512,N=256
    short* PB1Tp = PB1q  + 131072;             // K=256,N=512
    short* zpA   = PB1Tp + 131072;             // 16 MB

    prep<<<2560, 256, 0, stream>>>(W1, W2, z, PBSq, PBSp, PB2, PB2T,
                                   PB1q, PB1Tp, zpA);
    mega<<<512, 512, 0, stream>>>(zpA, PB1q, PB2, PB2T, PBSq, PBSp,
                                  b1, b2, W3, PB1Tp, z, out);
}

// Round 9
// 219.497 us; speedup vs baseline: 1.0551x; 1.0405x over previous
//
#include <hip/hip_runtime.h>
#include <math.h>

#define DT 0.1f

typedef __attribute__((ext_vector_type(4)))  short short4v;
typedef __attribute__((ext_vector_type(8)))  short short8;
typedef __attribute__((ext_vector_type(16))) float f32x16;

__device__ __forceinline__ short f2bf(float x) {
    unsigned int u = __float_as_uint(x);
    unsigned int r = (u + 0x7fffu + ((u >> 16) & 1u)) >> 16;  // RNE
    return (short)r;
}
__device__ __forceinline__ float bf2f(short s) {
    return __uint_as_float(((unsigned int)(unsigned short)s) << 16);
}
__device__ __forceinline__ float tanh_fast(float x) {
    float e = __expf(x + x);
    float r = __builtin_amdgcn_rcpf(e + 1.f);
    return __builtin_fmaf(-2.f, r, 1.f);
}
// HW packed f32->bf16 RNE (no builtin on gfx950)
__device__ __forceinline__ unsigned cvt_pk_bf16(float a, float b) {
    unsigned r;
    asm("v_cvt_pk_bf16_f32 %0, %1, %2" : "=v"(r) : "v"(a), "v"(b));
    return r;
}

// ---------------- weight packing: 32x32x16 MFMA B-fragment order -----------
// lane holds B[k = kt*16 + (lane>>5)*8 + j][n = nt*32 + (lane&31)]
// at out[((nt*KT + kt)*64 + lane)*8 + j],  KT = K/16
__device__ __forceinline__ void pack32_body(const float* __restrict__ W,
                                            short* __restrict__ out,
                                            int K, int N, int idx, bool trans)
{
    int j = idx & 7, lane = (idx >> 3) & 63, rest = idx >> 9;
    int KT = K >> 4;
    int kt = rest % KT, nt = rest / KT;
    int k = kt * 16 + (lane >> 5) * 8 + j;
    int n = nt * 32 + (lane & 31);
    out[idx] = f2bf(trans ? W[n * K + k] : W[k * N + n]);
}

// One launch for ALL preprocessing (same block map as R1).
__global__ __launch_bounds__(256)
void prep(const float* __restrict__ W1, const float* __restrict__ W2,
          const float* __restrict__ z,
          short* __restrict__ PBSq, short* __restrict__ PBSp,
          short* __restrict__ PB2, short* __restrict__ PB2T,
          short* __restrict__ PB1q, short* __restrict__ PB1Tp,
          short* __restrict__ zpA)
{
    __shared__ short zb[32 * 520];
    const int tid = threadIdx.x;
    const int b = blockIdx.x;

    if (b < 512) {
        // S_qp = -0.5*dt * W1^T[:, :512] @ W1[512:, :]   (b <  256, k = b)
        // S_pq =      dt * W1^T[:, 512:] @ W1[:512, :]   (b >= 256, k = b-256)
        const int n = tid;
        float s[8];
#pragma unroll
        for (int i = 0; i < 8; ++i) s[i] = 0.f;
        int k; float coef; short* dst;
        if (b < 256) {
            k = b; coef = -0.5f * DT; dst = PBSq;
            for (int c = 0; c < 512; c += 8) {
#pragma unroll
                for (int i = 0; i < 8; ++i)
                    s[i] = __builtin_fmaf(W1[(c + i) * 256 + k],
                                          W1[(512 + c + i) * 256 + n], s[i]);
            }
        } else {
            k = b - 256; coef = DT; dst = PBSp;
            for (int c = 0; c < 512; c += 8) {
#pragma unroll
                for (int i = 0; i < 8; ++i)
                    s[i] = __builtin_fmaf(W1[(512 + c + i) * 256 + k],
                                          W1[(c + i) * 256 + n], s[i]);
            }
        }
        float v = coef * (((s[0] + s[1]) + (s[2] + s[3])) +
                          ((s[4] + s[5]) + (s[6] + s[7])));
        int kt = k >> 4, r = k & 15;
        int lane = (r >> 3) * 32 + (n & 31), nt = n >> 5;
        dst[(((nt * 16 + kt) * 64 + lane) << 3) + (r & 7)] = f2bf(v);
    } else if (b < 768) {
        pack32_body(W2, PB2, 256, 256, (b - 512) * 256 + tid, false);
    } else if (b < 1024) {
        pack32_body(W2, PB2T, 256, 256, (b - 768) * 256 + tid, true);
    } else if (b < 1536) {
        pack32_body(W1, PB1q, 512, 256, (b - 1024) * 256 + tid, false);
    } else if (b < 2048) {
        pack32_body(W1 + 512 * 256, PB1Tp, 256, 512, (b - 1536) * 256 + tid, true);
    } else {
        // z (16384x512 fp32) -> A-frag-packed bf16, coalesced via LDS staging.
        const int bx = b - 2048;               // 512 blocks x 32 rows
#pragma unroll
        for (int j = 0; j < 16; ++j) {
            int lin = j * 256 + tid;           // 4096 float4
            int r = lin >> 7, c4 = lin & 127;
            float4 v = ((const float4*)z)[(size_t)(bx * 32 + r) * 128 + c4];
            uint2 pk;
            pk.x = cvt_pk_bf16(v.x, v.y);
            pk.y = cvt_pk_bf16(v.z, v.w);
            *(uint2*)&zb[r * 520 + c4 * 4] = pk;
        }
        __syncthreads();
        const int lane = tid & 63, w = tid >> 6;
        const int m = lane & 31, lh = lane >> 5;
#pragma unroll
        for (int j = 0; j < 8; ++j) {
            int kt = w * 8 + j;
            short8 f = *(const short8*)&zb[m * 520 + kt * 16 + lh * 8];
            *(short8*)(zpA + (((size_t)bx * 32 + kt) * 64 + lane) * 8) = f;
        }
    }
}

// ---------------- LDS tile layout, 32-row block version (verified R2/R3) ---
// tile nt: 64 slots x 16 shorts; rot = ((l31>>2)&3)*4
__device__ __forceinline__ short8 lds_frag32(const short* Ac, int kt,
                                             int l31, int lh, int rot)
{
    int nt_s = kt >> 1;
    int po = (((kt & 1) * 2 + lh) * 4 + rot) & 15;
    int base = (nt_s * 64 + l31) * 16 + po;
    short4v x = *(const short4v*)&Ac[base];
    short4v y = *(const short4v*)&Ac[base + 512];   // slot l31+32, same tile
    short8 r;
    r[0] = x.x; r[1] = x.y; r[2] = x.z; r[3] = x.w;
    r[4] = y.x; r[5] = y.y; r[6] = y.z; r[7] = y.w;
    return r;
}

// K=256 gemm, single 32x32 output tile per wave.
// SLIM: pb[4] (16 VGPR) + pa depth 2 (8 VGPR); acc in AGPR.
__device__ __forceinline__ void gemm_nt32(const short* Ac, int l31, int lh, int rot,
                                          const short8* __restrict__ Bf, f32x16& acc)
{
    short8 pb[4];
#pragma unroll
    for (int k = 0; k < 4; ++k) pb[k] = Bf[k * 64];
    short8 pa0 = lds_frag32(Ac, 0, l31, lh, rot);
    short8 pa1 = lds_frag32(Ac, 1, l31, lh, rot);
#pragma unroll
    for (int kt = 0; kt < 16; ++kt) {
        short8 ca = pa0, cb = pb[kt & 3];
        pa0 = pa1;
        if (kt + 2 < 16) pa1 = lds_frag32(Ac, kt + 2, l31, lh, rot);
        if (kt + 4 < 16) pb[kt & 3] = Bf[(kt + 4) * 64];
        acc = __builtin_amdgcn_mfma_f32_32x32x16_bf16(ca, cb, acc, 0, 0, 0);
    }
}

// ---------------- fused leapfrog: 32 rows/block, 512 blocks ----------------
// Register plan (the R1-R8 lesson): allocation = VGPR + AGPR (unified file).
// Target = 128 total/wave -> 4 waves/SIMD (2 blocks/CU, LDS 2x32KB fits).
// amdgpu_waves_per_eu(4) sets the 128 budget but lets the allocator split
// VGPR/AGPR freely (vs launch_bounds(512,4)'s hard VGPR=64 cap that spilled
// in R8: WRITE 100MB). VGPR demand is slimmed to ~75 by computing the
// elementwise phases in 4-float chunks (no f32x16 temporaries); AGPR = 48
// (A1, dsum, t0). Spill tripwire: FETCH ~30MB / WRITE ~33MB.
__global__ __launch_bounds__(512) __attribute__((amdgpu_waves_per_eu(4)))
void mega(const short* __restrict__ zpA,
          const short* __restrict__ PB1q,
          const short* __restrict__ PB2,
          const short* __restrict__ PB2T,
          const short* __restrict__ PBSq,
          const short* __restrict__ PBSp,
          const float* __restrict__ b1,
          const float* __restrict__ b2,
          const float* __restrict__ W3,
          const short* __restrict__ PB1Tp,
          const float* __restrict__ z,
          float* __restrict__ out)
{
    __shared__ alignas(16) short smem[16384];   // 32 KB -> 2 blocks/CU LDS-ok
    short* h1_c = smem;             // 8 nt x 64 x 16
    short* da_c = smem + 8192;

    const int tid = threadIdx.x;
    const int lane = tid & 63, w = tid >> 6;   // w = nt strip, 0..7
    const int l31 = lane & 31, lh = lane >> 5;
    const int rot = ((l31 >> 2) & 3) * 4;
    const int bx = blockIdx.x;                 // 512 blocks x 32 rows

    const int col = w * 32 + l31;
    const float b1v = b1[col], b2v = b2[col], w3v = W3[col];
    const int basei = (w * 64 + lane) * 16;    // own-tile base (nt = w)

    f32x16 A1 = 0.f;
    f32x16 dsum = 0.f;

    // GEMM1: A1 = z @ W1[:512,:]  (K=512, A frags from global, KT=32)
    {
        const short8* Af = (const short8*)zpA + ((size_t)bx * 32) * 64 + lane;
        const short8* Bf = (const short8*)PB1q + ((size_t)w * 32) * 64 + lane;
        short8 pa[2], pb[4];
#pragma unroll
        for (int k = 0; k < 2; ++k) pa[k] = Af[k * 64];
#pragma unroll
        for (int k = 0; k < 4; ++k) pb[k] = Bf[k * 64];
#pragma unroll
        for (int kt = 0; kt < 32; ++kt) {
            short8 ca = pa[kt & 1], cb = pb[kt & 3];
            if (kt + 2 < 32) pa[kt & 1] = Af[(kt + 2) * 64];
            if (kt + 4 < 32) pb[kt & 3] = Bf[(kt + 4) * 64];
            A1 = __builtin_amdgcn_mfma_f32_32x32x16_bf16(ca, cb, A1, 0, 0, 0);
        }
    }

    for (int it = 0; it < 8; ++it) {
        const bool isq = ((it % 3) == 1);

        // P1: h1 = tanh(A1 + b1)   (4-float chunks: <=6 live VGPR temps)
#pragma unroll
        for (int c = 0; c < 4; ++c) {
            float x0 = tanh_fast(A1[4 * c + 0] + b1v);
            float x1 = tanh_fast(A1[4 * c + 1] + b1v);
            float x2 = tanh_fast(A1[4 * c + 2] + b1v);
            float x3 = tanh_fast(A1[4 * c + 3] + b1v);
            uint2 pk;
            pk.x = cvt_pk_bf16(x0, x1);
            pk.y = cvt_pk_bf16(x2, x3);
            *(uint2*)&h1_c[basei + ((4 * c + rot) & 15)] = pk;
        }
        __syncthreads();

        // P2: da2 = W3*(1-tanh^2(h1@W2 + b2))
        {
            f32x16 t0 = 0.f;
            gemm_nt32(h1_c, l31, lh, rot,
                      (const short8*)PB2 + ((size_t)w * 16) * 64 + lane, t0);
#pragma unroll
            for (int c = 0; c < 4; ++c) {
                float x0 = tanh_fast(t0[4 * c + 0] + b2v);
                float x1 = tanh_fast(t0[4 * c + 1] + b2v);
                float x2 = tanh_fast(t0[4 * c + 2] + b2v);
                float x3 = tanh_fast(t0[4 * c + 3] + b2v);
                x0 = w3v * (1.f - x0 * x0); x1 = w3v * (1.f - x1 * x1);
                x2 = w3v * (1.f - x2 * x2); x3 = w3v * (1.f - x3 * x3);
                uint2 pk;
                pk.x = cvt_pk_bf16(x0, x1);
                pk.y = cvt_pk_bf16(x2, x3);
                *(uint2*)&da_c[basei + ((4 * c + rot) & 15)] = pk;
            }
        }
        __syncthreads();

        // P3: da1 = (da2@W2^T) * (1-h1^2)
        {
            f32x16 t0 = 0.f;
            gemm_nt32(da_c, l31, lh, rot,
                      (const short8*)PB2T + ((size_t)w * 16) * 64 + lane, t0);
            __syncthreads();   // all waves done reading da2
#pragma unroll
            for (int c = 0; c < 4; ++c) {
                short4v h4 = *(const short4v*)&h1_c[basei + ((4 * c + rot) & 15)];
                float h0 = bf2f(h4.x), h1f = bf2f(h4.y);
                float h2 = bf2f(h4.z), h3 = bf2f(h4.w);
                float d0 = t0[4 * c + 0] * (1.f - h0 * h0);
                float d1 = t0[4 * c + 1] * (1.f - h1f * h1f);
                float d2 = t0[4 * c + 2] * (1.f - h2 * h2);
                float d3 = t0[4 * c + 3] * (1.f - h3 * h3);
                if (isq) {
                    dsum[4 * c + 0] += d0; dsum[4 * c + 1] += d1;
                    dsum[4 * c + 2] += d2; dsum[4 * c + 3] += d3;
                }
                uint2 pk;
                pk.x = cvt_pk_bf16(d0, d1);
                pk.y = cvt_pk_bf16(d2, d3);
                *(uint2*)&da_c[basei + ((4 * c + rot) & 15)] = pk;
            }
        }
        __syncthreads();

        // P4: A1 += da1 @ S  (coef folded into S; skip on last eval)
        if (it < 7) {
            const short* S = isq ? PBSp : PBSq;
            gemm_nt32(da_c, l31, lh, rot,
                      (const short8*)S + ((size_t)w * 16) * 64 + lane, A1);
            // safe: every wave's P4 reads complete before it reaches the
            // next-iteration P1 barrier, which precedes any da_c overwrite.
        }
    }

    // ---- fused out-gemm: C = dsum @ W1^T[:,512:], out = z + DT*C ----------
#pragma unroll
    for (int c = 0; c < 4; ++c) {
        uint2 pk;
        pk.x = cvt_pk_bf16(dsum[4 * c + 0], dsum[4 * c + 1]);
        pk.y = cvt_pk_bf16(dsum[4 * c + 2], dsum[4 * c + 3]);
        *(uint2*)&da_c[basei + ((4 * c + rot) & 15)] = pk;
    }
    __syncthreads();

    // wave w -> output col-tiles {2w, 2w+1} (cols [w*64, w*64+64))
    f32x16 acc2[2];
    acc2[0] = 0.f; acc2[1] = 0.f;
    {
        const short8* Bf0 = (const short8*)PB1Tp + (size_t)(2 * w + 0) * 16 * 64 + lane;
        const short8* Bf1 = (const short8*)PB1Tp + (size_t)(2 * w + 1) * 16 * 64 + lane;
        short8 pb0[2], pb1[2];
#pragma unroll
        for (int k = 0; k < 2; ++k) { pb0[k] = Bf0[k * 64]; pb1[k] = Bf1[k * 64]; }
        short8 pa0 = lds_frag32(da_c, 0, l31, lh, rot);
        short8 pa1 = lds_frag32(da_c, 1, l31, lh, rot);
#pragma unroll
        for (int kt = 0; kt < 16; ++kt) {
            short8 ca = pa0, cb0 = pb0[kt & 1], cb1 = pb1[kt & 1];
            pa0 = pa1;
            if (kt + 2 < 16) {
                pa1 = lds_frag32(da_c, kt + 2, l31, lh, rot);
                pb0[kt & 1] = Bf0[(kt + 2) * 64];
                pb1[kt & 1] = Bf1[(kt + 2) * 64];
            }
            acc2[0] = __builtin_amdgcn_mfma_f32_32x32x16_bf16(ca, cb0, acc2[0], 0, 0, 0);
            acc2[1] = __builtin_amdgcn_mfma_f32_32x32x16_bf16(ca, cb1, acc2[1], 0, 0, 0);
        }
    }
    __syncthreads();   // all A-frag reads of da_c done before Ct overwrite

    // coalesced epilogue via LDS fp32 (reuses the 32 KB), two 256-col passes
    float* Ct = (float*)smem;                 // 32 x 256 fp32 = 32 KB
#pragma unroll
    for (int p = 0; p < 2; ++p) {
        if ((w >> 2) == p) {                  // waves owning cols [p*256, p*256+256)
#pragma unroll
            for (int t = 0; t < 2; ++t) {
                const int cl = (w & 3) * 64 + t * 32 + l31;
#pragma unroll
                for (int r = 0; r < 16; ++r) {
                    int row = (r & 3) + 8 * (r >> 2) + 4 * lh;
                    Ct[row * 256 + cl] = acc2[t][r];
                }
            }
        }
        __syncthreads();
#pragma unroll
        for (int j = 0; j < 4; ++j) {
            int lin = j * 512 + tid;          // 2048 float4 per pass
            int r = lin >> 6, c4 = lin & 63;
            size_t gi = (size_t)(bx * 32 + r) * 128 + p * 64 + c4;
            float4 zv = ((const float4*)z)[gi];
            float4 cv = *(const float4*)&Ct[r * 256 + c4 * 4];
            float4 ov;
            ov.x = zv.x + DT * cv.x; ov.y = zv.y + DT * cv.y;
            ov.z = zv.z + DT * cv.z; ov.w = zv.w + DT * cv.w;
            ((float4*)out)[gi] = ov;
        }
        __syncthreads();
    }
}

extern "C" void kernel_launch(void* const* d_in, const int* in_sizes, int n_in,
                              void* d_out, int out_size, void* d_ws, size_t ws_size,
                              hipStream_t stream)
{
    const float* z  = (const float*)d_in[0];
    const float* W1 = (const float*)d_in[1];   // 1024 x 256
    const float* b1 = (const float*)d_in[2];
    const float* W2 = (const float*)d_in[3];   // 256 x 256
    const float* b2 = (const float*)d_in[4];
    const float* W3 = (const float*)d_in[5];   // 256 x 1
    float* out = (float*)d_out;

    short* PB2   = (short*)d_ws;
    short* PB2T  = PB2   + 65536;
    short* PBSq  = PB2T  + 65536;
    short* PBSp  = PBSq  + 65536;
    short* PB1q  = PBSp  + 65536;              // K=512,N=256
    short* PB1Tp = PB1q  + 131072;             // K=256,N=512
    short* zpA   = PB1Tp + 131072;             // 16 MB

    prep<<<2560, 256, 0, stream>>>(W1, W2, z, PBSq, PBSp, PB2, PB2T,
                                   PB1q, PB1Tp, zpA);
    mega<<<512, 512, 0, stream>>>(zpA, PB1q, PB2, PB2T, PBSq, PBSp,
                                  b1, b2, W3, PB1Tp, z, out);
}